// Round 11
// baseline (1456.380 us; speedup 1.0000x reference)
//
#include <hip/hip_runtime.h>

#define NLAYER 4
#define M_TOK 32768

typedef unsigned short u16;
typedef __bf16 bf16x8 __attribute__((ext_vector_type(8)));
typedef float f32x4 __attribute__((ext_vector_type(4)));

__device__ inline float bf2f(u16 u) {
    union { unsigned int i; float f; } x; x.i = ((unsigned int)u) << 16; return x.f;
}
__device__ inline u16 f2bf(float f) {
    union { float f; unsigned int i; } x; x.f = f;
    return (u16)((x.i + 0x8000u) >> 16);
}
__device__ inline bf16x8 ld_frag(const u16* p) {
    union { uint4 u; bf16x8 b; } c; c.u = *(const uint4*)p; return c.b;
}
__device__ inline unsigned pk2(float a, float b) {
    union { float f; unsigned i; } ua, ub; ua.f = a; ub.f = b;
    return __builtin_amdgcn_perm(ub.i + 0x8000u, ua.i + 0x8000u, 0x07060302u);
}
__device__ inline float gelu_f(float x) {
    float z = 0.7978845608028654f * (x + 0.044715f * x * x * x);
    float t = 1.f - 2.f / (__expf(2.f * z) + 1.f);
    return 0.5f * x * (1.f + t);
}
__device__ inline void gload_lds16(const u16* g, u16* l) {
    __builtin_amdgcn_global_load_lds(
        (const __attribute__((address_space(1))) unsigned int*)g,
        (__attribute__((address_space(3))) unsigned int*)l, 16, 0, 0);
}

#define BAR()   asm volatile("s_barrier" ::: "memory")
#define WAIT4() asm volatile("s_waitcnt vmcnt(4)" ::: "memory")
#define WAIT0() asm volatile("s_waitcnt vmcnt(0)" ::: "memory")
#define LGKM0() asm volatile("s_waitcnt lgkmcnt(0)" ::: "memory")

// ---------------- dtype sniff ----------------
__global__ void sniff_kernel(const u16* __restrict__ raw, int* __restrict__ flag)
{
    if (threadIdx.x == 0 && blockIdx.x == 0) {
        int ok = 1;
        for (int i = 0; i < 32; i++) {
            u16 u = raw[i];
            int e = (u >> 7) & 0xFF;
            if (!(u == 0 || (e >= 90 && e <= 140))) ok = 0;
        }
        *flag = ok;
    }
}

// ---------------- single-launch ingest ----------------
struct IngestArgs { const void* src[20]; int off[21]; };
__global__ __launch_bounds__(256) void ingest_all(
    IngestArgs a, float* __restrict__ dst, const int* __restrict__ flag, int tot)
{
    int gid = blockIdx.x * 256 + threadIdx.x;
    if (gid >= tot) return;
    int lo = 0, hi = 20;
    while (hi - lo > 1) { int mid = (lo + hi) >> 1; if (gid >= a.off[mid]) lo = mid; else hi = mid; }
    int local = gid - a.off[lo];
    if (*flag) dst[gid] = bf2f(((const u16*)a.src[lo])[local]);
    else       dst[gid] = ((const float*)a.src[lo])[local];
}

// ---------------- weight packing ----------------
__global__ __launch_bounds__(256) void pack_qkv(
    const float* __restrict__ wq, const float* __restrict__ wk, const float* __restrict__ wv,
    const float* __restrict__ bq, const float* __restrict__ bk, const float* __restrict__ bv,
    u16* __restrict__ wT, float* __restrict__ bT)
{
    int l = blockIdx.y;
    int idx = blockIdx.x * 256 + threadIdx.x;
    int n = idx >> 8, k = idx & 255;
    const float* w = (n < 256) ? wq : (n < 512) ? wk : wv;
    int nn = n & 255;
    wT[(size_t)l * 768 * 256 + idx] = f2bf(w[(size_t)l * 65536 + k * 256 + nn]);
    if (idx < 768) {
        const float* bb = (idx < 256) ? bq : (idx < 512) ? bk : bv;
        bT[l * 768 + idx] = bb[l * 256 + (idx & 255)];
    }
}

__global__ __launch_bounds__(256) void pack_t(
    const float* __restrict__ src, u16* __restrict__ dst, int R, int C)
{
    int l = blockIdx.y;
    int idx = blockIdx.x * 256 + threadIdx.x;
    int c = idx / R, r = idx % R;
    size_t base = (size_t)l * R * C;
    dst[base + idx] = f2bf(src[base + (size_t)r * C + c]);
}

// ---------------- embedding ----------------
__global__ __launch_bounds__(256) void embed_kernel(
    const int* __restrict__ ids, const float* __restrict__ emb, float* __restrict__ x)
{
    int t = blockIdx.x * 256 + threadIdx.x;
    int row = t >> 6, c = (t & 63) * 4;
    int id = ids[row];
    float4 e = *(const float4*)(emb + (size_t)id * 256 + c);
    *(float4*)(x + (size_t)row * 256 + c) = e;
}

// ---------------- layernorm ----------------
__global__ __launch_bounds__(256) void ln_kernel(
    const float* __restrict__ x, const float* __restrict__ g, const float* __restrict__ b,
    u16* __restrict__ out)
{
    int row = blockIdx.x * 4 + (threadIdx.x >> 6);
    int lane = threadIdx.x & 63;
    float4 v = *(const float4*)(x + (size_t)row * 256 + lane * 4);
    float s = v.x + v.y + v.z + v.w;
    float s2 = v.x * v.x + v.y * v.y + v.z * v.z + v.w * v.w;
    #pragma unroll
    for (int mk = 1; mk < 64; mk <<= 1) {
        s += __shfl_xor(s, mk, 64);
        s2 += __shfl_xor(s2, mk, 64);
    }
    float mean = s * (1.f / 256.f);
    float var = s2 * (1.f / 256.f) - mean * mean;
    float rstd = rsqrtf(var + 1e-5f);
    int d0 = lane * 4;
    float4 gg = *(const float4*)(g + d0);
    float4 bb = *(const float4*)(b + d0);
    union { unsigned long long u; u16 q[4]; } oo;
    oo.q[0] = f2bf((v.x - mean) * rstd * gg.x + bb.x);
    oo.q[1] = f2bf((v.y - mean) * rstd * gg.y + bb.y);
    oo.q[2] = f2bf((v.z - mean) * rstd * gg.z + bb.z);
    oo.q[3] = f2bf((v.w - mean) * rstd * gg.w + bb.w);
    *(unsigned long long*)(out + (size_t)row * 256 + d0) = oo.u;
}

// ---------------- GEMM: 128x128 tile, BK=32, raw-barrier double-buffered DMA ----------------
template <int EPI, int K>
__global__ __launch_bounds__(256, 3) void gemm_db(
    const u16* __restrict__ A, const u16* __restrict__ Bt, const float* __restrict__ bias,
    u16* __restrict__ outB, float* __restrict__ resid, int N)
{
    __shared__ u16 lds[17408];
    constexpr int NC = K / 32;
    int tid = threadIdx.x, lane = tid & 63, wave = tid >> 6;
    int col = lane & 15, quad = lane >> 4;
    int wm = (wave >> 1) * 64, wn = (wave & 1) * 64;
    int bm = blockIdx.x * 128, bn = blockIdx.y * 128;

    u16* A0 = lds;          u16* A1 = lds + 4096;
    u16* B0 = lds + 8192;   u16* B1 = lds + 12288;

    int rL = wave * 32 + (lane >> 2);
    int sx = (lane & 3) ^ ((lane >> 2) & 3);
    const u16* srcA0 = A + (size_t)(bm + rL) * K + sx * 8;
    const u16* srcB0 = Bt + (size_t)(bn + rL) * K + sx * 8;
    int st = wave * 1024 + lane * 8;

    int g8 = (quad ^ (col & 3)) * 8;
    int aoff = (wm + col) * 32 + g8;
    int boff = (wn + col) * 32 + g8;

    f32x4 z4 = { 0.f, 0.f, 0.f, 0.f };
    f32x4 acc[4][4];
    #pragma unroll
    for (int i = 0; i < 4; i++)
        #pragma unroll
        for (int j = 0; j < 4; j++) acc[i][j] = z4;

    #define STAGE(c, Ax, Bx) do {                                        \
        const u16* _a = srcA0 + (c) * 32;                                \
        const u16* _b = srcB0 + (c) * 32;                                \
        gload_lds16(_a, (Ax) + st);                                      \
        gload_lds16(_a + (size_t)16 * K, (Ax) + st + 512);               \
        gload_lds16(_b, (Bx) + st);                                      \
        gload_lds16(_b + (size_t)16 * K, (Bx) + st + 512);               \
    } while (0)

    #define CHUNK(Ax, Bx) do {                                           \
        bf16x8 af[4], bfv[4];                                            \
        _Pragma("unroll")                                                \
        for (int i = 0; i < 4; i++) af[i] = ld_frag((Ax) + aoff + i * 512); \
        _Pragma("unroll")                                                \
        for (int j = 0; j < 4; j++) bfv[j] = ld_frag((Bx) + boff + j * 512); \
        _Pragma("unroll")                                                \
        for (int i = 0; i < 4; i++)                                      \
            _Pragma("unroll")                                            \
            for (int j = 0; j < 4; j++)                                  \
                acc[i][j] = __builtin_amdgcn_mfma_f32_16x16x32_bf16(af[i], bfv[j], acc[i][j], 0, 0, 0); \
    } while (0)

    STAGE(0, A0, B0);
    for (int c = 0; c < NC - 2; c += 2) {
        STAGE(c + 1, A1, B1);
        WAIT4(); BAR();
        CHUNK(A0, B0);
        LGKM0(); BAR();
        STAGE(c + 2, A0, B0);
        WAIT4(); BAR();
        CHUNK(A1, B1);
        LGKM0(); BAR();
    }
    STAGE(NC - 1, A1, B1);
    WAIT4(); BAR();
    CHUNK(A0, B0);
    LGKM0(); BAR();
    WAIT0(); BAR();
    CHUNK(A1, B1);
    __syncthreads();

    if (EPI == 2) {
        float* Cf = (float*)lds;
        #pragma unroll
        for (int h = 0; h < 2; h++) {
            if ((wave & 1) == h) {
                #pragma unroll
                for (int j = 0; j < 4; j++) {
                    float bv = bias[bn + wn + j * 16 + col];
                    #pragma unroll
                    for (int i = 0; i < 4; i++) {
                        int rl = wm + i * 16 + quad * 4;
                        #pragma unroll
                        for (int r = 0; r < 4; r++)
                            Cf[(rl + r) * 68 + j * 16 + col] = acc[i][j][r] + bv;
                    }
                }
            }
            LGKM0(); BAR();
            #pragma unroll
            for (int u = 0; u < 8; u++) {
                int row = u * 16 + (tid >> 4);
                int cseg = (tid & 15) * 4;
                float* rp = resid + (size_t)(bm + row) * N + bn + h * 64 + cseg;
                const float* cp = Cf + row * 68 + cseg;
                float4 rv = *(float4*)rp;
                float4 cv = *(const float4*)cp;
                rv.x += cv.x; rv.y += cv.y; rv.z += cv.z; rv.w += cv.w;
                *(float4*)rp = rv;
            }
            LGKM0(); BAR();
        }
    } else {
        u16* Cs = lds;
        #pragma unroll
        for (int j = 0; j < 4; j++) {
            int ccl = wn + j * 16 + col;
            float bv = bias[bn + ccl];
            #pragma unroll
            for (int i = 0; i < 4; i++) {
                int rl = wm + i * 16 + quad * 4;
                #pragma unroll
                for (int r = 0; r < 4; r++) {
                    float v = acc[i][j][r] + bv;
                    if (EPI == 1) v = gelu_f(v);
                    Cs[(rl + r) * 136 + ccl] = f2bf(v);
                }
            }
        }
        __syncthreads();
        #pragma unroll
        for (int u = 0; u < 8; u++) {
            int row = u * 16 + (tid >> 4);
            int c8 = (tid & 15) * 8;
            u16* op = outB + (size_t)(bm + row) * N + bn + c8;
            *(uint4*)op = *(const uint4*)(Cs + row * 136 + c8);
        }
    }
    #undef STAGE
    #undef CHUNK
}

// ---------------- sliding-window attention, S^T formulation ----------------
// Staging: register-prefetch pipeline with raw barriers (loads for chunk c+1 stay in
// flight through chunk c's compute); V^T staged via paired-key u32 writes (conflict-free).
__global__ __launch_bounds__(256, 4) void attn_kernel(
    const u16* __restrict__ qkv, u16* __restrict__ attno)
{
    __shared__ u16 Ks[64 * 72];
    __shared__ u16 Vt[64 * 68];
    __shared__ u16 Ps[4 * 16 * 72];
    int g = blockIdx.x;
    int xc = g & 7, t = g >> 3;
    int r12 = t & 15, s8 = t >> 4;
    int ng = s8 * 8 + xc;
    int bb = ng >> 4, nn = ng & 15;
    int hh = r12 & 3, t2 = r12 >> 2;
    int tid = threadIdx.x, lane = tid & 63, wave = tid >> 6;
    int q16 = lane & 15, quad = lane >> 4;
    float slope = exp2f(-2.f * (float)(hh + 1));
    float slopeL = slope * 1.44269504f;
    const float C1 = 0.125f * 1.44269504f;

    int qt0 = t2 * 2;
    size_t tok0 = (size_t)bb * 8192 + nn * 512;

    bf16x8 bqf[2][2];
    {
        int qrow = t2 * 128 + wave * 16 + q16;
        const u16* qp = qkv + (tok0 + qrow) * 768 + hh * 64 + quad * 8;
        bqf[0][0] = ld_frag(qp);
        bqf[0][1] = ld_frag(qp + 32);
        const u16* qp1 = qp + (size_t)64 * 768;
        bqf[1][0] = ld_frag(qp1);
        bqf[1][1] = ld_frag(qp1 + 32);
    }

    f32x4 z4 = { 0.f, 0.f, 0.f, 0.f };
    f32x4 oa[2][4];
    #pragma unroll
    for (int s = 0; s < 2; s++)
        #pragma unroll
        for (int dt = 0; dt < 4; dt++) oa[s][dt] = z4;
    float lsum[2] = { 0.f, 0.f };
    u16* Psw = Ps + wave * (16 * 72);

    int c_lo = (nn == 0) ? 8 : qt0;
    int c_hi = qt0 + 9;

    // staging maps: K rows kkK,kkK+32 (b128 writes, 2-way); V paired keys kk2,kk2+1
    int kkK = tid >> 3, c8k = (tid & 7) * 8;
    int kk2 = (tid & 31) * 2, c8v = (tid >> 5) * 8;

    uint4 pk0, pk1, pv0, pv1;
    auto load_c = [&](int c) {
        int tok = (int)tok0 - 512 + c * 64;
        const u16* bK = qkv + (size_t)(tok + kkK) * 768 + hh * 64 + 256 + c8k;
        pk0 = *(const uint4*)bK;
        pk1 = *(const uint4*)(bK + (size_t)32 * 768);
        const u16* bV = qkv + (size_t)(tok + kk2) * 768 + hh * 64 + 512 + c8v;
        pv0 = *(const uint4*)bV;
        pv1 = *(const uint4*)(bV + 768);
    };
    load_c(c_lo);

    for (int c = c_lo; c <= c_hi; ++c) {
        LGKM0(); BAR();                    // prior chunk's LDS reads complete everywhere
        *(uint4*)(Ks + kkK * 72 + c8k) = pk0;
        *(uint4*)(Ks + (kkK + 32) * 72 + c8k) = pk1;
        {
            union { uint4 u; u16 s[8]; } a, b;
            a.u = pv0; b.u = pv1;
            #pragma unroll
            for (int j = 0; j < 8; j++) {
                unsigned w = (unsigned)a.s[j] | ((unsigned)b.s[j] << 16);
                *(unsigned*)(Vt + (c8v + j) * 68 + kk2) = w;
            }
        }
        if (c < c_hi) load_c(c + 1);       // prefetch stays in flight through compute
        LGKM0(); BAR();                    // ds_writes visible; vmcnt NOT drained

        bf16x8 kf[4][2];
        #pragma unroll
        for (int kt = 0; kt < 4; kt++)
            #pragma unroll
            for (int ks = 0; ks < 2; ks++)
                kf[kt][ks] = ld_frag(Ks + (kt * 16 + q16) * 72 + ks * 32 + quad * 8);
        bf16x8 vf[4][2];
        #pragma unroll
        for (int dt = 0; dt < 4; dt++)
            #pragma unroll
            for (int ks = 0; ks < 2; ks++) {
                union { uint2 p[2]; bf16x8 b; } cv;
                const u16* vp = Vt + (dt * 16 + q16) * 68 + ks * 32 + quad * 8;
                cv.p[0] = *(const uint2*)(vp);
                cv.p[1] = *(const uint2*)(vp + 4);
                vf[dt][ks] = cv.b;
            }

        int act0 = (c <= qt0 + 8);
        int act1 = (c >= qt0 + 1);
        #pragma unroll
        for (int s = 0; s < 2; s++) {
            if (s == 0 ? !act0 : !act1) continue;
            f32x4 st[4];
            #pragma unroll
            for (int kt = 0; kt < 4; kt++) {
                f32x4 z = z4;
                #pragma unroll
                for (int ks = 0; ks < 2; ks++)
                    z = __builtin_amdgcn_mfma_f32_16x16x32_bf16(kf[kt][ks], bqf[s][ks], z, 0, 0, 0);
                st[kt] = z;
            }
            int qg = t2 * 128 + s * 64 + wave * 16 + q16;
            int D = 512 + qg - c * 64 - quad * 4;
            float nb = -slopeL * (float)D;
            int qts = qt0 + s;
            int diag = (c == qts) || (c == qts + 8);
            float ls = 0.f;
            #pragma unroll
            for (int kt = 0; kt < 4; kt++) {
                float pk[4];
                #pragma unroll
                for (int r = 0; r < 4; r++) {
                    float bias = fmaf(slopeL, (float)(kt * 16 + r), nb);
                    float p = exp2f(fmaf(st[kt][r], C1, bias));
                    if (diag) {
                        int dd = D - (kt * 16 + r);
                        p = ((unsigned)dd <= 512u) ? p : 0.f;
                    }
                    ls += p; pk[r] = p;
                }
                uint2 w;
                w.x = pk2(pk[0], pk[1]);
                w.y = pk2(pk[2], pk[3]);
                *(uint2*)(Psw + q16 * 72 + kt * 16 + quad * 4) = w;
            }
            lsum[s] += ls;
            bf16x8 pf[2];
            #pragma unroll
            for (int ks = 0; ks < 2; ks++)
                pf[ks] = ld_frag(Psw + q16 * 72 + ks * 32 + quad * 8);
            #pragma unroll
            for (int dt = 0; dt < 4; dt++)
                #pragma unroll
                for (int ks = 0; ks < 2; ks++)
                    oa[s][dt] = __builtin_amdgcn_mfma_f32_16x16x32_bf16(pf[ks], vf[dt][ks], oa[s][dt], 0, 0, 0);
        }
    }

    #pragma unroll
    for (int s = 0; s < 2; s++) {
        float lr = lsum[s];
        lr += __shfl_xor(lr, 16, 64);
        lr += __shfl_xor(lr, 32, 64);
        lsum[s] = lr;
    }
    float* lx = (float*)Psw;
    if (quad == 0) { lx[q16] = lsum[0]; lx[16 + q16] = lsum[1]; }
    #pragma unroll
    for (int s = 0; s < 2; s++) {
        float4 lq = *(const float4*)(lx + s * 16 + quad * 4);
        float inv[4] = { 1.f / lq.x, 1.f / lq.y, 1.f / lq.z, 1.f / lq.w };
        int tokb = (int)tok0 + t2 * 128 + s * 64 + wave * 16 + quad * 4;
        #pragma unroll
        for (int r = 0; r < 4; r++)
            #pragma unroll
            for (int dt = 0; dt < 4; dt++)
                attno[(size_t)(tokb + r) * 256 + hh * 64 + dt * 16 + q16] = f2bf(oa[s][dt][r] * inv[r]);
    }
}

// ---------------- LM head with fused final layernorm ----------------
__global__ __launch_bounds__(256) void head_ln_kernel(
    const float* __restrict__ x, const float* __restrict__ g, const float* __restrict__ b,
    const float* __restrict__ hw, const int* __restrict__ flag,
    u16* __restrict__ outb, float* __restrict__ outf)
{
    __shared__ float Wt[14 * 256];
    int tid = threadIdx.x;
    for (int i = tid; i < 14 * 256; i += 256) {
        int v = i >> 8, d = i & 255;
        Wt[i] = hw[d * 14 + v];
    }
    __syncthreads();
    int wave = tid >> 6, lane = tid & 63;
    int row = blockIdx.x * 4 + wave;
    float4 v = *(const float4*)(x + (size_t)row * 256 + lane * 4);
    float s = v.x + v.y + v.z + v.w;
    float s2 = v.x * v.x + v.y * v.y + v.z * v.z + v.w * v.w;
    #pragma unroll
    for (int mk = 1; mk < 64; mk <<= 1) {
        s += __shfl_xor(s, mk, 64);
        s2 += __shfl_xor(s2, mk, 64);
    }
    float mean = s * (1.f / 256.f);
    float var = s2 * (1.f / 256.f) - mean * mean;
    float rstd = rsqrtf(var + 1e-5f);
    int d0 = lane * 4;
    float4 gg = *(const float4*)(g + d0);
    float4 bb = *(const float4*)(b + d0);
    float hv[4];
    hv[0] = (v.x - mean) * rstd * gg.x + bb.x;
    hv[1] = (v.y - mean) * rstd * gg.y + bb.y;
    hv[2] = (v.z - mean) * rstd * gg.z + bb.z;
    hv[3] = (v.w - mean) * rstd * gg.w + bb.w;
    int isbf = *flag;
    for (int vv = 0; vv < 14; vv++) {
        float4 wv4 = *(const float4*)(Wt + vv * 256 + lane * 4);
        float sd = hv[0] * wv4.x + hv[1] * wv4.y + hv[2] * wv4.z + hv[3] * wv4.w;
        #pragma unroll
        for (int mk = 1; mk < 64; mk <<= 1) sd += __shfl_xor(sd, mk, 64);
        if (lane == 0) {
            if (isbf) outb[(size_t)row * 14 + vv] = f2bf(sd);
            else      outf[(size_t)row * 14 + vv] = sd;
        }
    }
}

extern "C" void kernel_launch(void* const* d_in, const int* in_sizes, int n_in,
                              void* d_out, int out_size, void* d_ws, size_t ws_size,
                              hipStream_t stream) {
    (void)out_size; (void)ws_size;
    const int* ids = (const int*)d_in[0];

    char* ws = (char*)d_ws;
    int* flag = (int*)ws; ws += 16;

    IngestArgs ia;
    int off = 0;
    for (int i = 1; i < n_in && i <= 20; i++) {
        ia.src[i - 1] = d_in[i];
        ia.off[i - 1] = off;
        off += in_sizes[i];
    }
    ia.off[20] = off;
    float* fbase = (float*)ws;
    ws += (size_t)((off + 3) & ~3) * 4;
    float* fin[21];
    for (int i = 1; i <= 20; i++) fin[i] = fbase + ia.off[i - 1];

    float* x    = (float*)ws;  ws += (size_t)M_TOK * 256 * 4;
    u16* h      = (u16*)ws;    ws += (size_t)M_TOK * 256 * 2;
    u16* qkv    = (u16*)ws;    ws += (size_t)M_TOK * 768 * 2;
    u16* attno  = (u16*)ws;    ws += (size_t)M_TOK * 256 * 2;
    u16* ff     = (u16*)ws;    ws += (size_t)M_TOK * 1024 * 2;
    u16* wqkvT  = (u16*)ws;    ws += (size_t)NLAYER * 768 * 256 * 2;
    u16* woT    = (u16*)ws;    ws += (size_t)NLAYER * 256 * 256 * 2;
    u16* w1T    = (u16*)ws;    ws += (size_t)NLAYER * 1024 * 256 * 2;
    u16* w2T    = (u16*)ws;    ws += (size_t)NLAYER * 256 * 1024 * 2;
    float* bqkv = (float*)ws;  ws += (size_t)NLAYER * 768 * 4;

    sniff_kernel<<<1, 64, 0, stream>>>((const u16*)d_in[1], flag);
    ingest_all<<<(off + 255) / 256, 256, 0, stream>>>(ia, fbase, flag, off);

    pack_qkv<<<dim3(768, NLAYER), 256, 0, stream>>>(fin[2], fin[4], fin[6],
                                                    fin[3], fin[5], fin[7], wqkvT, bqkv);
    pack_t<<<dim3(256, NLAYER), 256, 0, stream>>>(fin[8], woT, 256, 256);
    pack_t<<<dim3(1024, NLAYER), 256, 0, stream>>>(fin[14], w1T, 256, 1024);
    pack_t<<<dim3(1024, NLAYER), 256, 0, stream>>>(fin[16], w2T, 1024, 256);

    embed_kernel<<<8192, 256, 0, stream>>>(ids, fin[1], x);

    for (int l = 0; l < NLAYER; ++l) {
        ln_kernel<<<8192, 256, 0, stream>>>(x, fin[10] + l * 256, fin[11] + l * 256, h);
        gemm_db<0, 256><<<dim3(256, 6), 256, 0, stream>>>(h, wqkvT + (size_t)l * 768 * 256,
                                                          bqkv + l * 768, qkv, nullptr, 768);
        attn_kernel<<<1024, 256, 0, stream>>>(qkv, attno);
        gemm_db<2, 256><<<dim3(256, 2), 256, 0, stream>>>(attno, woT + (size_t)l * 65536,
                                                          fin[9] + l * 256, nullptr, x, 256);
        ln_kernel<<<8192, 256, 0, stream>>>(x, fin[12] + l * 256, fin[13] + l * 256, h);
        gemm_db<1, 256><<<dim3(256, 8), 256, 0, stream>>>(h, w1T + (size_t)l * 262144,
                                                          fin[15] + l * 1024, ff, nullptr, 1024);
        gemm_db<2, 1024><<<dim3(256, 2), 256, 0, stream>>>(ff, w2T + (size_t)l * 262144,
                                                           fin[17] + l * 256, nullptr, x, 256);
    }
    head_ln_kernel<<<8192, 256, 0, stream>>>(x, fin[18], fin[19], fin[20], flag,
                                             (u16*)d_out, (float*)d_out);
}

// Round 12
// 1052.990 us; speedup vs baseline: 1.3831x; 1.3831x over previous
//
#include <hip/hip_runtime.h>

#define NLAYER 4
#define M_TOK 32768

typedef unsigned short u16;
typedef __bf16 bf16x8 __attribute__((ext_vector_type(8)));
typedef float f32x4 __attribute__((ext_vector_type(4)));

__device__ inline float bf2f(u16 u) {
    union { unsigned int i; float f; } x; x.i = ((unsigned int)u) << 16; return x.f;
}
__device__ inline u16 f2bf(float f) {
    union { float f; unsigned int i; } x; x.f = f;
    return (u16)((x.i + 0x8000u) >> 16);
}
__device__ inline bf16x8 ld_frag(const u16* p) {
    union { uint4 u; bf16x8 b; } c; c.u = *(const uint4*)p; return c.b;
}
__device__ inline unsigned pk2(float a, float b) {
    union { float f; unsigned i; } ua, ub; ua.f = a; ub.f = b;
    return __builtin_amdgcn_perm(ub.i + 0x8000u, ua.i + 0x8000u, 0x07060302u);
}
__device__ inline float gelu_f(float x) {
    float z = 0.7978845608028654f * (x + 0.044715f * x * x * x);
    float t = 1.f - 2.f / (__expf(2.f * z) + 1.f);
    return 0.5f * x * (1.f + t);
}
__device__ inline void gload_lds16(const u16* g, u16* l) {
    __builtin_amdgcn_global_load_lds(
        (const __attribute__((address_space(1))) unsigned int*)g,
        (__attribute__((address_space(3))) unsigned int*)l, 16, 0, 0);
}

#define BAR()   asm volatile("s_barrier" ::: "memory")
#define WAIT4() asm volatile("s_waitcnt vmcnt(4)" ::: "memory")
#define WAIT0() asm volatile("s_waitcnt vmcnt(0)" ::: "memory")
#define LGKM0() asm volatile("s_waitcnt lgkmcnt(0)" ::: "memory")

// ---------------- dtype sniff ----------------
__global__ void sniff_kernel(const u16* __restrict__ raw, int* __restrict__ flag)
{
    if (threadIdx.x == 0 && blockIdx.x == 0) {
        int ok = 1;
        for (int i = 0; i < 32; i++) {
            u16 u = raw[i];
            int e = (u >> 7) & 0xFF;
            if (!(u == 0 || (e >= 90 && e <= 140))) ok = 0;
        }
        *flag = ok;
    }
}

// ---------------- single-launch ingest ----------------
struct IngestArgs { const void* src[20]; int off[21]; };
__global__ __launch_bounds__(256) void ingest_all(
    IngestArgs a, float* __restrict__ dst, const int* __restrict__ flag, int tot)
{
    int gid = blockIdx.x * 256 + threadIdx.x;
    if (gid >= tot) return;
    int lo = 0, hi = 20;
    while (hi - lo > 1) { int mid = (lo + hi) >> 1; if (gid >= a.off[mid]) lo = mid; else hi = mid; }
    int local = gid - a.off[lo];
    if (*flag) dst[gid] = bf2f(((const u16*)a.src[lo])[local]);
    else       dst[gid] = ((const float*)a.src[lo])[local];
}

// ---------------- weight packing ----------------
__global__ __launch_bounds__(256) void pack_qkv(
    const float* __restrict__ wq, const float* __restrict__ wk, const float* __restrict__ wv,
    const float* __restrict__ bq, const float* __restrict__ bk, const float* __restrict__ bv,
    u16* __restrict__ wT, float* __restrict__ bT)
{
    int l = blockIdx.y;
    int idx = blockIdx.x * 256 + threadIdx.x;
    int n = idx >> 8, k = idx & 255;
    const float* w = (n < 256) ? wq : (n < 512) ? wk : wv;
    int nn = n & 255;
    wT[(size_t)l * 768 * 256 + idx] = f2bf(w[(size_t)l * 65536 + k * 256 + nn]);
    if (idx < 768) {
        const float* bb = (idx < 256) ? bq : (idx < 512) ? bk : bv;
        bT[l * 768 + idx] = bb[l * 256 + (idx & 255)];
    }
}

__global__ __launch_bounds__(256) void pack_t(
    const float* __restrict__ src, u16* __restrict__ dst, int R, int C)
{
    int l = blockIdx.y;
    int idx = blockIdx.x * 256 + threadIdx.x;
    int c = idx / R, r = idx % R;
    size_t base = (size_t)l * R * C;
    dst[base + idx] = f2bf(src[base + (size_t)r * C + c]);
}

// ---------------- embedding ----------------
__global__ __launch_bounds__(256) void embed_kernel(
    const int* __restrict__ ids, const float* __restrict__ emb, float* __restrict__ x)
{
    int t = blockIdx.x * 256 + threadIdx.x;
    int row = t >> 6, c = (t & 63) * 4;
    int id = ids[row];
    float4 e = *(const float4*)(emb + (size_t)id * 256 + c);
    *(float4*)(x + (size_t)row * 256 + c) = e;
}

// ---------------- layernorm ----------------
__global__ __launch_bounds__(256) void ln_kernel(
    const float* __restrict__ x, const float* __restrict__ g, const float* __restrict__ b,
    u16* __restrict__ out)
{
    int row = blockIdx.x * 4 + (threadIdx.x >> 6);
    int lane = threadIdx.x & 63;
    float4 v = *(const float4*)(x + (size_t)row * 256 + lane * 4);
    float s = v.x + v.y + v.z + v.w;
    float s2 = v.x * v.x + v.y * v.y + v.z * v.z + v.w * v.w;
    #pragma unroll
    for (int mk = 1; mk < 64; mk <<= 1) {
        s += __shfl_xor(s, mk, 64);
        s2 += __shfl_xor(s2, mk, 64);
    }
    float mean = s * (1.f / 256.f);
    float var = s2 * (1.f / 256.f) - mean * mean;
    float rstd = rsqrtf(var + 1e-5f);
    int d0 = lane * 4;
    float4 gg = *(const float4*)(g + d0);
    float4 bb = *(const float4*)(b + d0);
    union { unsigned long long u; u16 q[4]; } oo;
    oo.q[0] = f2bf((v.x - mean) * rstd * gg.x + bb.x);
    oo.q[1] = f2bf((v.y - mean) * rstd * gg.y + bb.y);
    oo.q[2] = f2bf((v.z - mean) * rstd * gg.z + bb.z);
    oo.q[3] = f2bf((v.w - mean) * rstd * gg.w + bb.w);
    *(unsigned long long*)(out + (size_t)row * 256 + d0) = oo.u;
}

// ---------------- GEMM: 128x128 tile, BK=32, raw-barrier double-buffered DMA ----------------
template <int EPI, int K>
__global__ __launch_bounds__(256, 3) void gemm_db(
    const u16* __restrict__ A, const u16* __restrict__ Bt, const float* __restrict__ bias,
    u16* __restrict__ outB, float* __restrict__ resid, int N)
{
    __shared__ u16 lds[17408];
    constexpr int NC = K / 32;
    int tid = threadIdx.x, lane = tid & 63, wave = tid >> 6;
    int col = lane & 15, quad = lane >> 4;
    int wm = (wave >> 1) * 64, wn = (wave & 1) * 64;
    int bm = blockIdx.x * 128, bn = blockIdx.y * 128;

    u16* A0 = lds;          u16* A1 = lds + 4096;
    u16* B0 = lds + 8192;   u16* B1 = lds + 12288;

    int rL = wave * 32 + (lane >> 2);
    int sx = (lane & 3) ^ ((lane >> 2) & 3);
    const u16* srcA0 = A + (size_t)(bm + rL) * K + sx * 8;
    const u16* srcB0 = Bt + (size_t)(bn + rL) * K + sx * 8;
    int st = wave * 1024 + lane * 8;

    int g8 = (quad ^ (col & 3)) * 8;
    int aoff = (wm + col) * 32 + g8;
    int boff = (wn + col) * 32 + g8;

    f32x4 z4 = { 0.f, 0.f, 0.f, 0.f };
    f32x4 acc[4][4];
    #pragma unroll
    for (int i = 0; i < 4; i++)
        #pragma unroll
        for (int j = 0; j < 4; j++) acc[i][j] = z4;

    #define STAGE(c, Ax, Bx) do {                                        \
        const u16* _a = srcA0 + (c) * 32;                                \
        const u16* _b = srcB0 + (c) * 32;                                \
        gload_lds16(_a, (Ax) + st);                                      \
        gload_lds16(_a + (size_t)16 * K, (Ax) + st + 512);               \
        gload_lds16(_b, (Bx) + st);                                      \
        gload_lds16(_b + (size_t)16 * K, (Bx) + st + 512);               \
    } while (0)

    #define CHUNK(Ax, Bx) do {                                           \
        bf16x8 af[4], bfv[4];                                            \
        _Pragma("unroll")                                                \
        for (int i = 0; i < 4; i++) af[i] = ld_frag((Ax) + aoff + i * 512); \
        _Pragma("unroll")                                                \
        for (int j = 0; j < 4; j++) bfv[j] = ld_frag((Bx) + boff + j * 512); \
        _Pragma("unroll")                                                \
        for (int i = 0; i < 4; i++)                                      \
            _Pragma("unroll")                                            \
            for (int j = 0; j < 4; j++)                                  \
                acc[i][j] = __builtin_amdgcn_mfma_f32_16x16x32_bf16(af[i], bfv[j], acc[i][j], 0, 0, 0); \
    } while (0)

    STAGE(0, A0, B0);
    for (int c = 0; c < NC - 2; c += 2) {
        STAGE(c + 1, A1, B1);
        WAIT4(); BAR();
        CHUNK(A0, B0);
        LGKM0(); BAR();
        STAGE(c + 2, A0, B0);
        WAIT4(); BAR();
        CHUNK(A1, B1);
        LGKM0(); BAR();
    }
    STAGE(NC - 1, A1, B1);
    WAIT4(); BAR();
    CHUNK(A0, B0);
    LGKM0(); BAR();
    WAIT0(); BAR();
    CHUNK(A1, B1);
    __syncthreads();

    if (EPI == 2) {
        float* Cf = (float*)lds;
        #pragma unroll
        for (int h = 0; h < 2; h++) {
            if ((wave & 1) == h) {
                #pragma unroll
                for (int j = 0; j < 4; j++) {
                    float bv = bias[bn + wn + j * 16 + col];
                    #pragma unroll
                    for (int i = 0; i < 4; i++) {
                        int rl = wm + i * 16 + quad * 4;
                        #pragma unroll
                        for (int r = 0; r < 4; r++)
                            Cf[(rl + r) * 68 + j * 16 + col] = acc[i][j][r] + bv;
                    }
                }
            }
            LGKM0(); BAR();
            #pragma unroll
            for (int u = 0; u < 8; u++) {
                int row = u * 16 + (tid >> 4);
                int cseg = (tid & 15) * 4;
                float* rp = resid + (size_t)(bm + row) * N + bn + h * 64 + cseg;
                const float* cp = Cf + row * 68 + cseg;
                float4 rv = *(float4*)rp;
                float4 cv = *(const float4*)cp;
                rv.x += cv.x; rv.y += cv.y; rv.z += cv.z; rv.w += cv.w;
                *(float4*)rp = rv;
            }
            LGKM0(); BAR();
        }
    } else {
        u16* Cs = lds;
        #pragma unroll
        for (int j = 0; j < 4; j++) {
            int ccl = wn + j * 16 + col;
            float bv = bias[bn + ccl];
            #pragma unroll
            for (int i = 0; i < 4; i++) {
                int rl = wm + i * 16 + quad * 4;
                #pragma unroll
                for (int r = 0; r < 4; r++) {
                    float v = acc[i][j][r] + bv;
                    if (EPI == 1) v = gelu_f(v);
                    Cs[(rl + r) * 136 + ccl] = f2bf(v);
                }
            }
        }
        __syncthreads();
        #pragma unroll
        for (int u = 0; u < 8; u++) {
            int row = u * 16 + (tid >> 4);
            int c8 = (tid & 15) * 8;
            u16* op = outB + (size_t)(bm + row) * N + bn + c8;
            *(uint4*)op = *(const uint4*)(Cs + row * 136 + c8);
        }
    }
    #undef STAGE
    #undef CHUNK
}

// ---------------- sliding-window attention, S^T formulation ----------------
// Register-prefetch pipeline with raw barriers; V^T staged via paired-key u32 writes
// (conflict-free). launch_bounds (256,3): (256,4) capped VGPR at 64 -> scratch spill
// (round 11: FETCH/WRITE +300 MB each). 3 waves/EU fits the ~100-reg working set.
__global__ __launch_bounds__(256, 3) void attn_kernel(
    const u16* __restrict__ qkv, u16* __restrict__ attno)
{
    __shared__ u16 Ks[64 * 72];
    __shared__ u16 Vt[64 * 68];
    __shared__ u16 Ps[4 * 16 * 72];
    int g = blockIdx.x;
    int xc = g & 7, t = g >> 3;
    int r12 = t & 15, s8 = t >> 4;
    int ng = s8 * 8 + xc;
    int bb = ng >> 4, nn = ng & 15;
    int hh = r12 & 3, t2 = r12 >> 2;
    int tid = threadIdx.x, lane = tid & 63, wave = tid >> 6;
    int q16 = lane & 15, quad = lane >> 4;
    float slope = exp2f(-2.f * (float)(hh + 1));
    float slopeL = slope * 1.44269504f;
    const float C1 = 0.125f * 1.44269504f;

    int qt0 = t2 * 2;
    size_t tok0 = (size_t)bb * 8192 + nn * 512;

    bf16x8 bqf[2][2];
    {
        int qrow = t2 * 128 + wave * 16 + q16;
        const u16* qp = qkv + (tok0 + qrow) * 768 + hh * 64 + quad * 8;
        bqf[0][0] = ld_frag(qp);
        bqf[0][1] = ld_frag(qp + 32);
        const u16* qp1 = qp + (size_t)64 * 768;
        bqf[1][0] = ld_frag(qp1);
        bqf[1][1] = ld_frag(qp1 + 32);
    }

    f32x4 z4 = { 0.f, 0.f, 0.f, 0.f };
    f32x4 oa[2][4];
    #pragma unroll
    for (int s = 0; s < 2; s++)
        #pragma unroll
        for (int dt = 0; dt < 4; dt++) oa[s][dt] = z4;
    float lsum[2] = { 0.f, 0.f };
    u16* Psw = Ps + wave * (16 * 72);

    int c_lo = (nn == 0) ? 8 : qt0;
    int c_hi = qt0 + 9;

    // staging maps: K rows kkK,kkK+32 (b128 writes, 2-way); V paired keys kk2,kk2+1
    int kkK = tid >> 3, c8k = (tid & 7) * 8;
    int kk2 = (tid & 31) * 2, c8v = (tid >> 5) * 8;

    uint4 pk0, pk1, pv0, pv1;
    auto load_c = [&](int c) {
        int tok = (int)tok0 - 512 + c * 64;
        const u16* bK = qkv + (size_t)(tok + kkK) * 768 + hh * 64 + 256 + c8k;
        pk0 = *(const uint4*)bK;
        pk1 = *(const uint4*)(bK + (size_t)32 * 768);
        const u16* bV = qkv + (size_t)(tok + kk2) * 768 + hh * 64 + 512 + c8v;
        pv0 = *(const uint4*)bV;
        pv1 = *(const uint4*)(bV + 768);
    };
    load_c(c_lo);

    for (int c = c_lo; c <= c_hi; ++c) {
        LGKM0(); BAR();                    // prior chunk's LDS reads complete everywhere
        *(uint4*)(Ks + kkK * 72 + c8k) = pk0;
        *(uint4*)(Ks + (kkK + 32) * 72 + c8k) = pk1;
        {
            union { uint4 u; u16 s[8]; } a, b;
            a.u = pv0; b.u = pv1;
            #pragma unroll
            for (int j = 0; j < 8; j++) {
                unsigned w = (unsigned)a.s[j] | ((unsigned)b.s[j] << 16);
                *(unsigned*)(Vt + (c8v + j) * 68 + kk2) = w;
            }
        }
        if (c < c_hi) load_c(c + 1);       // prefetch stays in flight through compute
        LGKM0(); BAR();                    // ds_writes visible; vmcnt NOT drained

        bf16x8 kf[4][2];
        #pragma unroll
        for (int kt = 0; kt < 4; kt++)
            #pragma unroll
            for (int ks = 0; ks < 2; ks++)
                kf[kt][ks] = ld_frag(Ks + (kt * 16 + q16) * 72 + ks * 32 + quad * 8);
        bf16x8 vf[4][2];
        #pragma unroll
        for (int dt = 0; dt < 4; dt++)
            #pragma unroll
            for (int ks = 0; ks < 2; ks++) {
                union { uint2 p[2]; bf16x8 b; } cv;
                const u16* vp = Vt + (dt * 16 + q16) * 68 + ks * 32 + quad * 8;
                cv.p[0] = *(const uint2*)(vp);
                cv.p[1] = *(const uint2*)(vp + 4);
                vf[dt][ks] = cv.b;
            }

        int act0 = (c <= qt0 + 8);
        int act1 = (c >= qt0 + 1);
        #pragma unroll
        for (int s = 0; s < 2; s++) {
            if (s == 0 ? !act0 : !act1) continue;
            f32x4 st[4];
            #pragma unroll
            for (int kt = 0; kt < 4; kt++) {
                f32x4 z = z4;
                #pragma unroll
                for (int ks = 0; ks < 2; ks++)
                    z = __builtin_amdgcn_mfma_f32_16x16x32_bf16(kf[kt][ks], bqf[s][ks], z, 0, 0, 0);
                st[kt] = z;
            }
            int qg = t2 * 128 + s * 64 + wave * 16 + q16;
            int D = 512 + qg - c * 64 - quad * 4;
            float nb = -slopeL * (float)D;
            int qts = qt0 + s;
            int diag = (c == qts) || (c == qts + 8);
            float ls = 0.f;
            #pragma unroll
            for (int kt = 0; kt < 4; kt++) {
                float pk[4];
                #pragma unroll
                for (int r = 0; r < 4; r++) {
                    float bias = fmaf(slopeL, (float)(kt * 16 + r), nb);
                    float p = exp2f(fmaf(st[kt][r], C1, bias));
                    if (diag) {
                        int dd = D - (kt * 16 + r);
                        p = ((unsigned)dd <= 512u) ? p : 0.f;
                    }
                    ls += p; pk[r] = p;
                }
                uint2 w;
                w.x = pk2(pk[0], pk[1]);
                w.y = pk2(pk[2], pk[3]);
                *(uint2*)(Psw + q16 * 72 + kt * 16 + quad * 4) = w;
            }
            lsum[s] += ls;
            bf16x8 pf[2];
            #pragma unroll
            for (int ks = 0; ks < 2; ks++)
                pf[ks] = ld_frag(Psw + q16 * 72 + ks * 32 + quad * 8);
            #pragma unroll
            for (int dt = 0; dt < 4; dt++)
                #pragma unroll
                for (int ks = 0; ks < 2; ks++)
                    oa[s][dt] = __builtin_amdgcn_mfma_f32_16x16x32_bf16(pf[ks], vf[dt][ks], oa[s][dt], 0, 0, 0);
        }
    }

    #pragma unroll
    for (int s = 0; s < 2; s++) {
        float lr = lsum[s];
        lr += __shfl_xor(lr, 16, 64);
        lr += __shfl_xor(lr, 32, 64);
        lsum[s] = lr;
    }
    float* lx = (float*)Psw;
    if (quad == 0) { lx[q16] = lsum[0]; lx[16 + q16] = lsum[1]; }
    #pragma unroll
    for (int s = 0; s < 2; s++) {
        float4 lq = *(const float4*)(lx + s * 16 + quad * 4);
        float inv[4] = { 1.f / lq.x, 1.f / lq.y, 1.f / lq.z, 1.f / lq.w };
        int tokb = (int)tok0 + t2 * 128 + s * 64 + wave * 16 + quad * 4;
        #pragma unroll
        for (int r = 0; r < 4; r++)
            #pragma unroll
            for (int dt = 0; dt < 4; dt++)
                attno[(size_t)(tokb + r) * 256 + hh * 64 + dt * 16 + q16] = f2bf(oa[s][dt][r] * inv[r]);
    }
}

// ---------------- LM head with fused final layernorm ----------------
__global__ __launch_bounds__(256) void head_ln_kernel(
    const float* __restrict__ x, const float* __restrict__ g, const float* __restrict__ b,
    const float* __restrict__ hw, const int* __restrict__ flag,
    u16* __restrict__ outb, float* __restrict__ outf)
{
    __shared__ float Wt[14 * 256];
    int tid = threadIdx.x;
    for (int i = tid; i < 14 * 256; i += 256) {
        int v = i >> 8, d = i & 255;
        Wt[i] = hw[d * 14 + v];
    }
    __syncthreads();
    int wave = tid >> 6, lane = tid & 63;
    int row = blockIdx.x * 4 + wave;
    float4 v = *(const float4*)(x + (size_t)row * 256 + lane * 4);
    float s = v.x + v.y + v.z + v.w;
    float s2 = v.x * v.x + v.y * v.y + v.z * v.z + v.w * v.w;
    #pragma unroll
    for (int mk = 1; mk < 64; mk <<= 1) {
        s += __shfl_xor(s, mk, 64);
        s2 += __shfl_xor(s2, mk, 64);
    }
    float mean = s * (1.f / 256.f);
    float var = s2 * (1.f / 256.f) - mean * mean;
    float rstd = rsqrtf(var + 1e-5f);
    int d0 = lane * 4;
    float4 gg = *(const float4*)(g + d0);
    float4 bb = *(const float4*)(b + d0);
    float hv[4];
    hv[0] = (v.x - mean) * rstd * gg.x + bb.x;
    hv[1] = (v.y - mean) * rstd * gg.y + bb.y;
    hv[2] = (v.z - mean) * rstd * gg.z + bb.z;
    hv[3] = (v.w - mean) * rstd * gg.w + bb.w;
    int isbf = *flag;
    for (int vv = 0; vv < 14; vv++) {
        float4 wv4 = *(const float4*)(Wt + vv * 256 + lane * 4);
        float sd = hv[0] * wv4.x + hv[1] * wv4.y + hv[2] * wv4.z + hv[3] * wv4.w;
        #pragma unroll
        for (int mk = 1; mk < 64; mk <<= 1) sd += __shfl_xor(sd, mk, 64);
        if (lane == 0) {
            if (isbf) outb[(size_t)row * 14 + vv] = f2bf(sd);
            else      outf[(size_t)row * 14 + vv] = sd;
        }
    }
}

extern "C" void kernel_launch(void* const* d_in, const int* in_sizes, int n_in,
                              void* d_out, int out_size, void* d_ws, size_t ws_size,
                              hipStream_t stream) {
    (void)out_size; (void)ws_size;
    const int* ids = (const int*)d_in[0];

    char* ws = (char*)d_ws;
    int* flag = (int*)ws; ws += 16;

    IngestArgs ia;
    int off = 0;
    for (int i = 1; i < n_in && i <= 20; i++) {
        ia.src[i - 1] = d_in[i];
        ia.off[i - 1] = off;
        off += in_sizes[i];
    }
    ia.off[20] = off;
    float* fbase = (float*)ws;
    ws += (size_t)((off + 3) & ~3) * 4;
    float* fin[21];
    for (int i = 1; i <= 20; i++) fin[i] = fbase + ia.off[i - 1];

    float* x    = (float*)ws;  ws += (size_t)M_TOK * 256 * 4;
    u16* h      = (u16*)ws;    ws += (size_t)M_TOK * 256 * 2;
    u16* qkv    = (u16*)ws;    ws += (size_t)M_TOK * 768 * 2;
    u16* attno  = (u16*)ws;    ws += (size_t)M_TOK * 256 * 2;
    u16* ff     = (u16*)ws;    ws += (size_t)M_TOK * 1024 * 2;
    u16* wqkvT  = (u16*)ws;    ws += (size_t)NLAYER * 768 * 256 * 2;
    u16* woT    = (u16*)ws;    ws += (size_t)NLAYER * 256 * 256 * 2;
    u16* w1T    = (u16*)ws;    ws += (size_t)NLAYER * 1024 * 256 * 2;
    u16* w2T    = (u16*)ws;    ws += (size_t)NLAYER * 256 * 1024 * 2;
    float* bqkv = (float*)ws;  ws += (size_t)NLAYER * 768 * 4;

    sniff_kernel<<<1, 64, 0, stream>>>((const u16*)d_in[1], flag);
    ingest_all<<<(off + 255) / 256, 256, 0, stream>>>(ia, fbase, flag, off);

    pack_qkv<<<dim3(768, NLAYER), 256, 0, stream>>>(fin[2], fin[4], fin[6],
                                                    fin[3], fin[5], fin[7], wqkvT, bqkv);
    pack_t<<<dim3(256, NLAYER), 256, 0, stream>>>(fin[8], woT, 256, 256);
    pack_t<<<dim3(1024, NLAYER), 256, 0, stream>>>(fin[14], w1T, 256, 1024);
    pack_t<<<dim3(1024, NLAYER), 256, 0, stream>>>(fin[16], w2T, 1024, 256);

    embed_kernel<<<8192, 256, 0, stream>>>(ids, fin[1], x);

    for (int l = 0; l < NLAYER; ++l) {
        ln_kernel<<<8192, 256, 0, stream>>>(x, fin[10] + l * 256, fin[11] + l * 256, h);
        gemm_db<0, 256><<<dim3(256, 6), 256, 0, stream>>>(h, wqkvT + (size_t)l * 768 * 256,
                                                          bqkv + l * 768, qkv, nullptr, 768);
        attn_kernel<<<1024, 256, 0, stream>>>(qkv, attno);
        gemm_db<2, 256><<<dim3(256, 2), 256, 0, stream>>>(attno, woT + (size_t)l * 65536,
                                                          fin[9] + l * 256, nullptr, x, 256);
        ln_kernel<<<8192, 256, 0, stream>>>(x, fin[12] + l * 256, fin[13] + l * 256, h);
        gemm_db<1, 256><<<dim3(256, 8), 256, 0, stream>>>(h, w1T + (size_t)l * 262144,
                                                          fin[15] + l * 1024, ff, nullptr, 1024);
        gemm_db<2, 1024><<<dim3(256, 2), 256, 0, stream>>>(ff, w2T + (size_t)l * 262144,
                                                           fin[17] + l * 256, nullptr, x, 256);
    }
    head_ln_kernel<<<8192, 256, 0, stream>>>(x, fin[18], fin[19], fin[20], flag,
                                             (u16*)d_out, (float*)d_out);
}